// Round 19
// baseline (39.492 us; speedup 1.0000x reference)
//
#include <hip/hip_runtime.h>

// Chamfer distance via MFMA: D[i][j] = ||p_i||^2 + ||r_j||^2 - 2 p_i.r_j
// computed entirely inside mfma_f32_16x16x32_f16 using K-slots:
//  (g,e) = (lane>>4, element idx) coordinates; A/B place paired values at the
//  SAME (g,e), so pairing is correct under any HW k-mapping bijection.
//  g0: A=[-2xh,-2xh,-2xl,-2yh,-2yh,-2yl, nh, nl]  B=[xh,xl,xh,yh,yl,yh, 8, 8]
//  g1: A=[8,8,0,...]                              B=[nh,nl,0,...]
//  (h/l = f16 hi/lo split of coord; n = ||q||^2/8 hi/lo; products sum to d^2)
// C/D layout (HW-verified): col=lane&15, row=(lane>>4)*4+reg.
// P-blocks (256): pts-tile (16) vs all refs -> rowmins in-block.
// R-blocks (256): 128 refs vs all pts -> refmins in-block. No atomics/memsets.

typedef _Float16 half8 __attribute__((ext_vector_type(8)));
typedef float f32x4 __attribute__((ext_vector_type(4)));

constexpr int N_PTS = 4096;
constexpr int M_REF = 32768;
// ws layout in uint4 units:
constexpr int APo = 0;                    // pts  A-format:  256 tiles * 64
constexpr int BPo = 16384;                // refs B-format: 2048 tiles * 64
constexpr int ARo = 16384 + 131072;       // refs A-format: 2048 tiles * 64
constexpr int BRo = 16384 + 2 * 131072;   // pts  B-format:  256 tiles * 64
constexpr int WS_U4 = BRo + 16384;        // partial[] floats start here

__device__ __forceinline__ unsigned int pk2(float a, float b) {
    _Float16 ha = (_Float16)a, hb = (_Float16)b;
    unsigned short ua = *(unsigned short*)&ha, ub = *(unsigned short*)&hb;
    return (unsigned int)ua | ((unsigned int)ub << 16);
}

// ---------------- Kernel 0: pack fragment buffers --------------------------
__global__ __launch_bounds__(256) void pack_kernel(
    const float2* __restrict__ pts, const float2* __restrict__ refs,
    uint4* __restrict__ ws4)
{
    const int gid = blockIdx.x * 256 + threadIdx.x;   // 144*256 = 36864
    float2 p; uint4 *Ad, *Bd;
    if (gid < N_PTS) {
        p = pts[gid];
        Ad = ws4 + APo + (gid >> 4) * 64 + (gid & 15);
        Bd = ws4 + BRo + (gid >> 4) * 64 + (gid & 15);
    } else {
        const int q = gid - N_PTS;
        p = refs[q];
        Ad = ws4 + ARo + (q >> 4) * 64 + (q & 15);
        Bd = ws4 + BPo + (q >> 4) * 64 + (q & 15);
    }
    const float x = p.x, y = p.y;
    const _Float16 xh = (_Float16)x; const float fxh = (float)xh, xl = x - fxh;
    const _Float16 yh = (_Float16)y; const float fyh = (float)yh, yl = y - fyh;
    const float n8 = fmaf(x, x, y * y) * 0.125f;
    const _Float16 nh = (_Float16)n8; const float fnh = (float)nh, nl = n8 - fnh;
    const uint4 z4 = make_uint4(0, 0, 0, 0);
    // A-format (own -2*coords + own norm + the 8-multipliers in g1)
    Ad[0]  = make_uint4(pk2(-2.f*fxh, -2.f*fxh), pk2(-2.f*xl, -2.f*fyh),
                        pk2(-2.f*fyh, -2.f*yl),  pk2(fnh, nl));
    Ad[16] = make_uint4(pk2(8.f, 8.f), 0, 0, 0);
    Ad[32] = z4; Ad[48] = z4;
    // B-format (raw coords + own norm in g1)
    Bd[0]  = make_uint4(pk2(fxh, xl), pk2(fxh, fyh), pk2(yl, fyh), pk2(8.f, 8.f));
    Bd[16] = make_uint4(pk2(fnh, nl), 0, 0, 0);
    Bd[32] = z4; Bd[48] = z4;
}

// ---------------- Kernel 1: MFMA chamfer, 512 blocks x 512 threads ---------
__global__ __launch_bounds__(512) void mfma_main(
    const uint4* __restrict__ ws4, float* __restrict__ partial)
{
    __shared__ float red[1152];
    const int tid = threadIdx.x, b = blockIdx.x;
    const int l = tid & 63, w = tid >> 6;
    const f32x4 zc = {0.f, 0.f, 0.f, 0.f};

    if (b < 256) {
        // ---- P: pts tile b (16 pts) vs ALL refs; wave w covers 256 j-tiles.
        uint4 ar = ws4[APo + b * 64 + l];
        const half8 A = *reinterpret_cast<half8*>(&ar);
        float a0 = 3e38f, a1 = 3e38f, a2 = 3e38f, a3 = 3e38f;
        const uint4* Bb = ws4 + BPo + (w * 256) * 64 + l;
        uint4 f0[8], f1[8];
        #pragma unroll
        for (int u = 0; u < 8; ++u) f0[u] = Bb[u * 64];
        for (int s = 0; s < 16; ++s) {
            #pragma unroll
            for (int u = 0; u < 8; ++u) f1[u] = Bb[(16 * s + 8 + u) * 64];
            #pragma unroll
            for (int u = 0; u < 8; ++u) {
                const half8 B = *reinterpret_cast<half8*>(&f0[u]);
                const f32x4 D = __builtin_amdgcn_mfma_f32_16x16x32_f16(A, B, zc, 0, 0, 0);
                a0 = fminf(a0, D[0]); a1 = fminf(a1, D[1]);
                a2 = fminf(a2, D[2]); a3 = fminf(a3, D[3]);
            }
            if (s < 15) {
                #pragma unroll
                for (int u = 0; u < 8; ++u) f0[u] = Bb[(16 * s + 16 + u) * 64];
            }
            #pragma unroll
            for (int u = 0; u < 8; ++u) {
                const half8 B = *reinterpret_cast<half8*>(&f1[u]);
                const f32x4 D = __builtin_amdgcn_mfma_f32_16x16x32_f16(A, B, zc, 0, 0, 0);
                a0 = fminf(a0, D[0]); a1 = fminf(a1, D[1]);
                a2 = fminf(a2, D[2]); a3 = fminf(a3, D[3]);
            }
        }
        #pragma unroll
        for (int m = 1; m < 16; m <<= 1) {       // min over the 16 cols (lanes)
            a0 = fminf(a0, __shfl_xor(a0, m, 64));
            a1 = fminf(a1, __shfl_xor(a1, m, 64));
            a2 = fminf(a2, __shfl_xor(a2, m, 64));
            a3 = fminf(a3, __shfl_xor(a3, m, 64));
        }
        if ((l & 15) == 0) {
            const int r0 = (l >> 4) * 4;
            red[w * 16 + r0 + 0] = a0; red[w * 16 + r0 + 1] = a1;
            red[w * 16 + r0 + 2] = a2; red[w * 16 + r0 + 3] = a3;
        }
        __syncthreads();
        if (tid < 16) {
            float m = red[tid];
            #pragma unroll
            for (int ww = 1; ww < 8; ++ww) m = fminf(m, red[ww * 16 + tid]);
            red[1024 + tid] = sqrtf(fmaxf(m, 1e-12f));
        }
        __syncthreads();
        if (tid == 0) {
            float s = 0.f;
            #pragma unroll
            for (int k = 0; k < 16; ++k) s += red[1024 + k];
            partial[b] = s;
        }
    } else {
        // ---- R: refs [rb*128,+128) as A (8 i-tiles) vs ALL pts; wave w: 32 j-tiles.
        const int rb = b - 256;
        half8 Am[8];
        #pragma unroll
        for (int m = 0; m < 8; ++m) {
            uint4 a = ws4[ARo + (rb * 8 + m) * 64 + l];
            Am[m] = *reinterpret_cast<half8*>(&a);
        }
        float acc[8][4];
        #pragma unroll
        for (int m = 0; m < 8; ++m)
            #pragma unroll
            for (int r = 0; r < 4; ++r) acc[m][r] = 3e38f;
        const uint4* Bb = ws4 + BRo + (w * 32) * 64 + l;
        uint4 c0[4], c1[4];
        #pragma unroll
        for (int u = 0; u < 4; ++u) c0[u] = Bb[u * 64];
        for (int s = 0; s < 4; ++s) {
            #pragma unroll
            for (int u = 0; u < 4; ++u) c1[u] = Bb[(8 * s + 4 + u) * 64];
            #pragma unroll
            for (int u = 0; u < 4; ++u) {
                const half8 B = *reinterpret_cast<half8*>(&c0[u]);
                #pragma unroll
                for (int m = 0; m < 8; ++m) {
                    const f32x4 D = __builtin_amdgcn_mfma_f32_16x16x32_f16(Am[m], B, zc, 0, 0, 0);
                    acc[m][0] = fminf(acc[m][0], D[0]); acc[m][1] = fminf(acc[m][1], D[1]);
                    acc[m][2] = fminf(acc[m][2], D[2]); acc[m][3] = fminf(acc[m][3], D[3]);
                }
            }
            if (s < 3) {
                #pragma unroll
                for (int u = 0; u < 4; ++u) c0[u] = Bb[(8 * s + 8 + u) * 64];
            }
            #pragma unroll
            for (int u = 0; u < 4; ++u) {
                const half8 B = *reinterpret_cast<half8*>(&c1[u]);
                #pragma unroll
                for (int m = 0; m < 8; ++m) {
                    const f32x4 D = __builtin_amdgcn_mfma_f32_16x16x32_f16(Am[m], B, zc, 0, 0, 0);
                    acc[m][0] = fminf(acc[m][0], D[0]); acc[m][1] = fminf(acc[m][1], D[1]);
                    acc[m][2] = fminf(acc[m][2], D[2]); acc[m][3] = fminf(acc[m][3], D[3]);
                }
            }
        }
        #pragma unroll
        for (int m = 0; m < 8; ++m)
            #pragma unroll
            for (int r = 0; r < 4; ++r)
                #pragma unroll
                for (int mk = 1; mk < 16; mk <<= 1)
                    acc[m][r] = fminf(acc[m][r], __shfl_xor(acc[m][r], mk, 64));
        if ((l & 15) == 0) {
            const int r0 = (l >> 4) * 4;
            #pragma unroll
            for (int m = 0; m < 8; ++m)
                #pragma unroll
                for (int r = 0; r < 4; ++r)
                    red[w * 128 + m * 16 + r0 + r] = acc[m][r];
        }
        __syncthreads();
        if (tid < 128) {
            float mn = red[tid];
            #pragma unroll
            for (int ww = 1; ww < 8; ++ww) mn = fminf(mn, red[ww * 128 + tid]);
            float d = sqrtf(fmaxf(mn, 1e-12f));
            #pragma unroll
            for (int off = 32; off > 0; off >>= 1) d += __shfl_down(d, off, 64);
            if ((tid & 63) == 0) red[1024 + (tid >> 6)] = d;
        }
        __syncthreads();
        if (tid == 0) partial[b] = red[1024] + red[1025];
    }
}

// ---------------- Kernel 2: sum 512 partials (plain store) -----------------
__global__ __launch_bounds__(512) void sum_kernel(
    const float* __restrict__ partial, float* __restrict__ out)
{
    __shared__ float ss[8];
    const int tid = threadIdx.x;
    float v = partial[tid];
    #pragma unroll
    for (int off = 32; off > 0; off >>= 1) v += __shfl_down(v, off, 64);
    if ((tid & 63) == 0) ss[tid >> 6] = v;
    __syncthreads();
    if (tid == 0) {
        float t = 0.f;
        #pragma unroll
        for (int k = 0; k < 8; ++k) t += ss[k];
        out[0] = t;
    }
}

extern "C" void kernel_launch(void* const* d_in, const int* in_sizes, int n_in,
                              void* d_out, int out_size, void* d_ws, size_t ws_size,
                              hipStream_t stream) {
    const float2* pts  = (const float2*)d_in[0];            // circle 0 (offset 0)
    const float2* refs = ((const float2*)d_in[1]) + M_REF;  // last (=2nd) skeleton slice

    uint4* ws4 = (uint4*)d_ws;
    float* partial = (float*)(ws4 + WS_U4);                 // [512]
    float* out = (float*)d_out;

    pack_kernel<<<144, 256, 0, stream>>>(pts, refs, ws4);
    mfma_main  <<<512, 512, 0, stream>>>(ws4, partial);
    sum_kernel <<<1, 512, 0, stream>>>(partial, out);
}